// Round 2
// 1739.588 us; speedup vs baseline: 1.6080x; 1.6080x over previous
//
#include <hip/hip_runtime.h>
#include <math.h>

#define S_LEN 1024
#define B_SZ 2
#define H_DIM 1024
#define NHQ 8
#define NKV 2
#define D_HEAD 128
#define NE 64
#define TOPK 8
#define NGRP 8
#define TGRP 4
#define FI_DIM 512
#define CAP 512
#define EPS_F 1e-5f
#define T_TOK (B_SZ * S_LEN)               // 2048
#define QKV_DIM ((NHQ + 2 * NKV) * D_HEAD) // 1536
#define SCALE_F 0.08838834764831845f       // 1/sqrt(128)

typedef __attribute__((ext_vector_type(8))) short short8;
typedef __attribute__((ext_vector_type(4))) float floatx4;

__device__ inline short f2bf(float f) {
  union { float f; unsigned u; } v; v.f = f;
  unsigned r = (v.u + 0x7FFFu + ((v.u >> 16) & 1u)) >> 16;
  return (short)(r & 0xFFFFu);
}
__device__ inline float bf2f(short s) {
  union { unsigned u; float f; } v; v.u = ((unsigned)(unsigned short)s) << 16;
  return v.f;
}

// ---------------- RMSNorm: writes bf16 always, fp32 optionally ----------------
__global__ __launch_bounds__(256) void rmsnorm_row(const float* __restrict__ x,
                                                   const float* __restrict__ w,
                                                   float* __restrict__ outf,
                                                   short* __restrict__ outb) {
  int t = blockIdx.x;
  int tid = threadIdx.x;
  const float* xp = x + (size_t)t * H_DIM;
  float4 v = *(const float4*)(xp + tid * 4);
  float ss = v.x * v.x + v.y * v.y + v.z * v.z + v.w * v.w;
  for (int i = 1; i < 64; i <<= 1) ss += __shfl_xor(ss, i);
  __shared__ float red[4];
  if ((tid & 63) == 0) red[tid >> 6] = ss;
  __syncthreads();
  float tot = red[0] + red[1] + red[2] + red[3];
  float rs = rsqrtf(tot / (float)H_DIM + EPS_F);
  float4 wv = *(const float4*)(w + tid * 4);
  float4 o;
  o.x = v.x * rs * wv.x; o.y = v.y * rs * wv.y;
  o.z = v.z * rs * wv.z; o.w = v.w * rs * wv.w;
  if (outf) *(float4*)(outf + (size_t)t * H_DIM + tid * 4) = o;
  short* bp = outb + (size_t)t * H_DIM + tid * 4;
  bp[0] = f2bf(o.x); bp[1] = f2bf(o.y); bp[2] = f2bf(o.z); bp[3] = f2bf(o.w);
}

// ---------------- MFMA NT GEMM: C[M,N] = A(bf16)[M,K] @ W(fp32)[N,K]^T (+bias)(+res) ----------------
__global__ __launch_bounds__(256) void gemm_nt_mfma(const short* __restrict__ A,
                                                    const float* __restrict__ W,
                                                    const float* __restrict__ bias,
                                                    const float* __restrict__ res,
                                                    float* __restrict__ C,
                                                    int M, int N, int K) {
  __shared__ __align__(16) short As[128 * 72];
  __shared__ __align__(16) short Bs[128 * 72];
  int tid = threadIdx.x;
  int m0 = blockIdx.y * 128, n0 = blockIdx.x * 128;
  int lane = tid & 63, wid = tid >> 6;
  int wm = (wid & 1) * 64, wn = (wid >> 1) * 64;
  floatx4 acc[4][4] = {};
  for (int k0 = 0; k0 < K; k0 += 64) {
    __syncthreads();
#pragma unroll
    for (int i = 0; i < 4; ++i) {
      int idx = tid + i * 256;
      int m = idx >> 3, c = idx & 7;
      *(int4*)(As + m * 72 + c * 8) = *(const int4*)(A + (size_t)(m0 + m) * K + k0 + c * 8);
    }
#pragma unroll
    for (int i = 0; i < 4; ++i) {
      int idx = tid + i * 256;
      int n = idx >> 3, c = idx & 7;
      const float* wp = W + (size_t)(n0 + n) * K + k0 + c * 8;
      float4 v0 = *(const float4*)(wp);
      float4 v1 = *(const float4*)(wp + 4);
      short8 b;
      b[0] = f2bf(v0.x); b[1] = f2bf(v0.y); b[2] = f2bf(v0.z); b[3] = f2bf(v0.w);
      b[4] = f2bf(v1.x); b[5] = f2bf(v1.y); b[6] = f2bf(v1.z); b[7] = f2bf(v1.w);
      *(short8*)(Bs + n * 72 + c * 8) = b;
    }
    __syncthreads();
#pragma unroll
    for (int ks = 0; ks < 2; ++ks) {
      int ko = ks * 32 + (lane >> 4) * 8;
      short8 af[4], bfg[4];
#pragma unroll
      for (int t = 0; t < 4; ++t)
        af[t] = *(const short8*)(As + (wm + t * 16 + (lane & 15)) * 72 + ko);
#pragma unroll
      for (int t = 0; t < 4; ++t)
        bfg[t] = *(const short8*)(Bs + (wn + t * 16 + (lane & 15)) * 72 + ko);
#pragma unroll
      for (int mt = 0; mt < 4; ++mt)
#pragma unroll
        for (int nt = 0; nt < 4; ++nt)
          acc[mt][nt] = __builtin_amdgcn_mfma_f32_16x16x32_bf16(af[mt], bfg[nt], acc[mt][nt], 0, 0, 0);
    }
  }
  int q = lane >> 4, cl = lane & 15;
#pragma unroll
  for (int mt = 0; mt < 4; ++mt)
#pragma unroll
    for (int nt = 0; nt < 4; ++nt)
#pragma unroll
      for (int r = 0; r < 4; ++r) {
        int m = m0 + wm + mt * 16 + q * 4 + r;
        int n = n0 + wn + nt * 16 + cl;
        float v = acc[mt][nt][r];
        if (bias) v += bias[n];
        if (res) v += res[(size_t)m * N + n];
        C[(size_t)m * N + n] = v;
      }
}

// ---------------- per-head q/k RMSNorm + partial rope; emits bf16 Q (pre-scaled),
// bf16 K, and bf16 transposed V for the MFMA attention ----------------
__global__ __launch_bounds__(64) void qknorm_rope(const float* __restrict__ qkv,
                                                  const int* __restrict__ positions,
                                                  const float* __restrict__ qn_w,
                                                  const float* __restrict__ kn_w,
                                                  short* __restrict__ qbo,
                                                  short* __restrict__ kbo,
                                                  short* __restrict__ vtbo) {
  int t = blockIdx.x;
  int head = blockIdx.y;
  int lane = threadIdx.x;
  int b = t >> 10;
  int s = t & (S_LEN - 1);
  if (head >= NHQ + NKV) {  // V heads: bf16 convert + transpose to [b][kvh][d][s]
    int kvh = head - (NHQ + NKV);
    const float* vp = qkv + (size_t)t * QKV_DIM + (NHQ + NKV) * D_HEAD + kvh * D_HEAD;
    short* vt = vtbo + (size_t)(b * NKV + kvh) * D_HEAD * S_LEN + s;
    vt[(size_t)lane * S_LEN] = f2bf(vp[lane]);
    vt[(size_t)(lane + 64) * S_LEN] = f2bf(vp[lane + 64]);
    return;
  }
  bool isq = head < NHQ;
  int off = isq ? head * D_HEAD : (NHQ * D_HEAD + (head - NHQ) * D_HEAD);
  const float* ptr = qkv + (size_t)t * QKV_DIM + off;
  const float* w = isq ? qn_w : kn_w;
  float x0 = ptr[lane];
  float x1 = ptr[lane + 64];
  float ss = x0 * x0 + x1 * x1;
  for (int i = 1; i < 64; i <<= 1) ss += __shfl_xor(ss, i);
  float rs = rsqrtf(ss / (float)D_HEAD + EPS_F);
  x0 = x0 * rs * w[lane];
  x1 = x1 * rs * w[lane + 64];
  float pos = (float)positions[s];
  int i2 = lane & 31;
  float invf = powf(10000.0f, -(float)i2 / 32.0f);
  float ang = pos * invf;
  float c = cosf(ang), sn = sinf(ang);
  float other = __shfl_xor(x0, 32);
  float r = (lane < 32) ? (x0 * c - other * sn) : (x0 * c + other * sn);
  if (isq) {
    short* qo = qbo + ((size_t)(b * NHQ + head) * S_LEN + s) * D_HEAD;
    qo[lane] = f2bf(r * SCALE_F);
    qo[lane + 64] = f2bf(x1 * SCALE_F);
  } else {
    short* ko = kbo + ((size_t)(b * NKV + (head - NHQ)) * S_LEN + s) * D_HEAD;
    ko[lane] = f2bf(r);
    ko[lane + 64] = f2bf(x1);
  }
}

// ---------------- MFMA flash attention (causal GQA), bf16 in, bf16 out ----------------
// 256 blocks x 4 waves; each wave owns 16 query rows of one (b,h).
// Waves of a block take q-tiles {g, 31-g, 32+g, 63-g} -> equal causal work per block.
// QK^T: A=Q (prescaled), B=K. PV: A=P (LDS transpose), B=V^T (pre-transposed global).
__global__ __launch_bounds__(256) void attn_mfma(const short* __restrict__ qb,
                                                 const short* __restrict__ kb,
                                                 const short* __restrict__ vtb,
                                                 short* __restrict__ attnout) {
  __shared__ __align__(16) short Pb[4][16 * 36];  // per-wave P tile, 72B stride (bank-conflict-free)
  int tid = threadIdx.x;
  int lane = tid & 63, wid = tid >> 6;
  int l15 = lane & 15, l4 = lane >> 4;
  int bx = blockIdx.x;
  int bh = bx >> 4;            // 0..15 = b*8+h
  int g = bx & 15;
  int qt = (wid == 0) ? g : (wid == 1) ? (31 - g) : (wid == 2) ? (32 + g) : (63 - g);
  int b = bh >> 3, h = bh & 7, kvh = h >> 2;
  int qb0 = qt * 16;
  short* Pw = Pb[wid];

  // Q A-fragments (row = l15, k-elems = l4*8.., 4 chunks of D)
  const short* qp = qb + ((size_t)(b * NHQ + h) * S_LEN + qb0 + l15) * D_HEAD + l4 * 8;
  short8 qf[4];
#pragma unroll
  for (int c = 0; c < 4; ++c) qf[c] = *(const short8*)(qp + c * 32);

  const short* kbp = kb + (size_t)(b * NKV + kvh) * S_LEN * D_HEAD;
  const short* vbp = vtb + (size_t)(b * NKV + kvh) * D_HEAD * S_LEN;

  float m[4] = {-1e30f, -1e30f, -1e30f, -1e30f};
  float l[4] = {0.f, 0.f, 0.f, 0.f};
  floatx4 o[8] = {};

  int nkt = qb0 / 32 + 1;  // only the last tile straddles the diagonal
  for (int kt = 0; kt < nkt; ++kt) {
    int kb0 = kt * 32;
    // scores: two 16-col tiles over D=128
    const short* kp = kbp + (size_t)(kb0 + l15) * D_HEAD + l4 * 8;
    floatx4 s0 = {}, s1 = {};
#pragma unroll
    for (int c = 0; c < 4; ++c) {
      short8 k0 = *(const short8*)(kp + c * 32);
      short8 k1 = *(const short8*)(kp + 16 * D_HEAD + c * 32);
      s0 = __builtin_amdgcn_mfma_f32_16x16x32_bf16(qf[c], k0, s0, 0, 0, 0);
      s1 = __builtin_amdgcn_mfma_f32_16x16x32_bf16(qf[c], k1, s1, 0, 0, 0);
    }
    if (kt == nkt - 1) {  // causal mask on diagonal tile
#pragma unroll
      for (int r = 0; r < 4; ++r) {
        int qrow = qb0 + l4 * 4 + r;
        if (kb0 + l15 > qrow) s0[r] = -1e30f;
        if (kb0 + 16 + l15 > qrow) s1[r] = -1e30f;
      }
    }
    // online softmax (rows live across 16-lane groups; C-layout row = l4*4+r)
    float al[4];
#pragma unroll
    for (int r = 0; r < 4; ++r) {
      float tm = fmaxf(s0[r], s1[r]);
      tm = fmaxf(tm, __shfl_xor(tm, 1));
      tm = fmaxf(tm, __shfl_xor(tm, 2));
      tm = fmaxf(tm, __shfl_xor(tm, 4));
      tm = fmaxf(tm, __shfl_xor(tm, 8));
      float mn = fmaxf(m[r], tm);
      al[r] = __expf(m[r] - mn);
      m[r] = mn;
      float p0 = __expf(s0[r] - mn);
      float p1 = __expf(s1[r] - mn);
      s0[r] = p0; s1[r] = p1;
      float ts = p0 + p1;
      ts += __shfl_xor(ts, 1);
      ts += __shfl_xor(ts, 2);
      ts += __shfl_xor(ts, 4);
      ts += __shfl_xor(ts, 8);
      l[r] = l[r] * al[r] + ts;
    }
#pragma unroll
    for (int dt = 0; dt < 8; ++dt)
#pragma unroll
      for (int r = 0; r < 4; ++r) o[dt][r] *= al[r];
    // P: C-layout -> A-layout via per-wave LDS (wave-local; no __syncthreads)
    __builtin_amdgcn_wave_barrier();
#pragma unroll
    for (int r = 0; r < 4; ++r) {
      int prow = l4 * 4 + r;
      Pw[prow * 36 + l15] = f2bf(s0[r]);
      Pw[prow * 36 + 16 + l15] = f2bf(s1[r]);
    }
    __builtin_amdgcn_wave_barrier();
    short4 pa0 = *(const short4*)(Pw + l15 * 36 + l4 * 8);
    short4 pa1 = *(const short4*)(Pw + l15 * 36 + l4 * 8 + 4);
    short8 pf;
    pf[0] = pa0.x; pf[1] = pa0.y; pf[2] = pa0.z; pf[3] = pa0.w;
    pf[4] = pa1.x; pf[5] = pa1.y; pf[6] = pa1.z; pf[7] = pa1.w;
    // PV: 8 d-tiles, B-fragments straight from transposed V
#pragma unroll
    for (int dt = 0; dt < 8; ++dt) {
      short8 vf = *(const short8*)(vbp + (size_t)(dt * 16 + l15) * S_LEN + kb0 + l4 * 8);
      o[dt] = __builtin_amdgcn_mfma_f32_16x16x32_bf16(pf, vf, o[dt], 0, 0, 0);
    }
  }
  float inv[4];
#pragma unroll
  for (int r = 0; r < 4; ++r) inv[r] = 1.f / l[r];
#pragma unroll
  for (int dt = 0; dt < 8; ++dt)
#pragma unroll
    for (int r = 0; r < 4; ++r) {
      int qrow = qb0 + l4 * 4 + r;
      attnout[(size_t)(b * S_LEN + qrow) * (NHQ * D_HEAD) + h * D_HEAD + dt * 16 + l15] =
          f2bf(o[dt][r] * inv[r]);
    }
}

// ---------------- MoE gating ----------------
__global__ __launch_bounds__(64) void gating_kernel(const float* __restrict__ xt,
                                                    const float* __restrict__ gate_w,
                                                    const float* __restrict__ gate_b,
                                                    int* __restrict__ topi,
                                                    float* __restrict__ fw) {
  __shared__ float xs[H_DIM];
  __shared__ float sc[NE];
  __shared__ float corr[NE];
  __shared__ float grp[NGRP];
  int t = blockIdx.x;
  int e = threadIdx.x;
  for (int i = e; i < H_DIM; i += 64) xs[i] = xt[(size_t)t * H_DIM + i];
  __syncthreads();
  const float* gw = gate_w + (size_t)e * H_DIM;
  float acc = 0.f;
  for (int h = 0; h < H_DIM; ++h) acc = fmaf(xs[h], gw[h], acc);
  float s = 1.f / (1.f + expf(-acc));
  sc[e] = s;
  corr[e] = s + gate_b[e];
  __syncthreads();
  if (e < NGRP) {
    float m1 = -1e30f, m2 = -1e30f;
    for (int j = 0; j < NE / NGRP; ++j) {
      float v = corr[e * 8 + j];
      if (v > m1) { m2 = m1; m1 = v; }
      else if (v > m2) m2 = v;
    }
    grp[e] = m1 + m2;
  }
  __syncthreads();
  if (e == 0) {
    bool gsel[NGRP];
    for (int g = 0; g < NGRP; ++g) gsel[g] = false;
    for (int it = 0; it < TGRP; ++it) {
      int bi = -1; float bv = -1e30f;
      for (int g = 0; g < NGRP; ++g)
        if (!gsel[g] && grp[g] > bv) { bv = grp[g]; bi = g; }
      gsel[bi] = true;
    }
    bool ch[NE];
    for (int i2 = 0; i2 < NE; ++i2) ch[i2] = false;
    int sel[TOPK];
    float wsum = 0.f;
    for (int it = 0; it < TOPK; ++it) {
      int bi = -1; float bv = -1e30f;
      for (int x2 = 0; x2 < NE; ++x2) {
        if (!gsel[x2 >> 3] || ch[x2]) continue;
        if (corr[x2] > bv) { bv = corr[x2]; bi = x2; }
      }
      ch[bi] = true;
      sel[it] = bi;
      wsum += sc[bi];
    }
    float inv = 1.f / wsum;
    for (int it = 0; it < TOPK; ++it) {
      topi[t * TOPK + it] = sel[it];
      fw[t * TOPK + it] = sc[sel[it]] * inv;
    }
  }
}

// ---------------- parallel ordered capacity scan: 1 block, 256 threads ----------------
__global__ __launch_bounds__(256) void scan_kernel(const int* __restrict__ topi,
                                                   int* __restrict__ perm,
                                                   int* __restrict__ ecnt) {
  __shared__ int hist[256 * 65];
  int tid = threadIdx.x;
  for (int i = tid; i < 256 * 65; i += 256) hist[i] = 0;
  __syncthreads();
  int loc[64];
#pragma unroll
  for (int j = 0; j < 64; j += 4) {
    int4 v = *(const int4*)(topi + tid * 64 + j);
    loc[j] = v.x; loc[j + 1] = v.y; loc[j + 2] = v.z; loc[j + 3] = v.w;
  }
#pragma unroll
  for (int j = 0; j < 64; ++j) hist[tid * 65 + loc[j]]++;
  __syncthreads();
  if (tid < 64) {
    int run = 0;
    for (int c = 0; c < 256; ++c) {
      int v = hist[c * 65 + tid];
      hist[c * 65 + tid] = run;
      run += v;
    }
    ecnt[tid] = run < CAP ? run : CAP;
  }
  __syncthreads();
#pragma unroll
  for (int j = 0; j < 64; ++j) {
    int e = loc[j];
    int pos = hist[tid * 65 + e]++;
    if (pos < CAP) perm[e * CAP + pos] = tid * 64 + j;
  }
}

__global__ void zero_kernel(float4* __restrict__ p) {
  p[(size_t)blockIdx.x * 256 + threadIdx.x] = make_float4(0.f, 0.f, 0.f, 0.f);
}

// ---------------- F1: act = silu(X Wg) * (X Wu), MFMA, bf16 out ----------------
__global__ __launch_bounds__(256) void moe_gu_mfma(const short* __restrict__ xtb,
                                                   const float* __restrict__ w_gu,
                                                   const float* __restrict__ sw_gu,
                                                   const int* __restrict__ perm,
                                                   const int* __restrict__ ecnt,
                                                   short* __restrict__ actR,
                                                   short* __restrict__ actS) {
  __shared__ int tok[128];
  __shared__ __align__(16) short As[128 * 72];
  __shared__ __align__(16) short Bs[128 * 72];
  int tid = threadIdx.x;
  int bx = blockIdx.x;
  int lane = tid & 63, wid = tid >> 6;
  bool sh = bx >= 256;
  int e = 0, base, rows;
  const float* wg;
  short* actp;
  if (!sh) {
    e = bx >> 2; base = (bx & 3) * 128;
    int cnt = ecnt[e];
    if (base >= cnt) return;
    rows = cnt - base; if (rows > 128) rows = 128;
    wg = w_gu + (size_t)e * H_DIM * (2 * FI_DIM);
    actp = actR + (size_t)(e * CAP + base) * FI_DIM;
  } else {
    base = (bx - 256) * 128; rows = 128;
    wg = sw_gu;
    actp = actS + (size_t)base * FI_DIM;
  }
  if (tid < 128) {
    int m = tid < rows ? tid : (rows - 1);
    tok[tid] = sh ? (base + tid) : (perm[e * CAP + base + m] >> 3);
  }
  __syncthreads();
  int mh = (wid & 1) * 64;
  int uh = wid >> 1;
  for (int jc = 0; jc < 8; ++jc) {
    floatx4 acc[4][4] = {};
    for (int k0 = 0; k0 < H_DIM; k0 += 64) {
      __syncthreads();
#pragma unroll
      for (int i = 0; i < 4; ++i) {
        int idx = tid + i * 256;
        int m = idx >> 3, c = idx & 7;
        *(int4*)(As + m * 72 + c * 8) =
            *(const int4*)(xtb + (size_t)tok[m] * H_DIM + k0 + c * 8);
      }
#pragma unroll
      for (int i = 0; i < 4; ++i) {
        int idx = tid + i * 256;
        int kc = idx >> 7, n2 = idx & 127;
        int col = (n2 < 64) ? (jc * 64 + n2) : (FI_DIM + jc * 64 + (n2 - 64));
        const float* wp = wg + (size_t)(k0 + kc * 8) * (2 * FI_DIM) + col;
        short8 b;
#pragma unroll
        for (int j = 0; j < 8; ++j) b[j] = f2bf(wp[(size_t)j * (2 * FI_DIM)]);
        *(short8*)(Bs + n2 * 72 + kc * 8) = b;
      }
      __syncthreads();
#pragma unroll
      for (int ks = 0; ks < 2; ++ks) {
        int ko = ks * 32 + (lane >> 4) * 8;
        short8 af[4], bfg[4];
#pragma unroll
        for (int t = 0; t < 4; ++t)
          af[t] = *(const short8*)(As + (mh + t * 16 + (lane & 15)) * 72 + ko);
#pragma unroll
        for (int t = 0; t < 4; ++t)
          bfg[t] = *(const short8*)(Bs + (uh * 64 + t * 16 + (lane & 15)) * 72 + ko);
#pragma unroll
        for (int mt = 0; mt < 4; ++mt)
#pragma unroll
          for (int nt = 0; nt < 4; ++nt)
            acc[mt][nt] = __builtin_amdgcn_mfma_f32_16x16x32_bf16(af[mt], bfg[nt], acc[mt][nt], 0, 0, 0);
      }
    }
    __syncthreads();
    int q = lane >> 4, cl = lane & 15;
    if (uh == 0) {
#pragma unroll
      for (int mt = 0; mt < 4; ++mt)
#pragma unroll
        for (int nt = 0; nt < 4; ++nt)
#pragma unroll
          for (int r = 0; r < 4; ++r) {
            int row = mh + mt * 16 + q * 4 + r;
            int col = nt * 16 + cl;
            Bs[row * 72 + col] = f2bf(acc[mt][nt][r]);
          }
    }
    __syncthreads();
    if (uh == 1) {
#pragma unroll
      for (int mt = 0; mt < 4; ++mt)
#pragma unroll
        for (int nt = 0; nt < 4; ++nt)
#pragma unroll
          for (int r = 0; r < 4; ++r) {
            int row = mh + mt * 16 + q * 4 + r;
            int col = nt * 16 + cl;
            float g = bf2f(Bs[row * 72 + col]);
            float u = acc[mt][nt][r];
            float a = g / (1.f + expf(-g)) * u;
            actp[(size_t)row * FI_DIM + jc * 64 + col] = f2bf(a);
          }
    }
  }
}

// ---------------- F2: out += (act Wdn) * w, MFMA, atomic scatter ----------------
__global__ __launch_bounds__(256) void moe_dn_mfma(const short* __restrict__ actR,
                                                   const short* __restrict__ actS,
                                                   const float* __restrict__ w_dn,
                                                   const float* __restrict__ sw_dn,
                                                   const int* __restrict__ perm,
                                                   const int* __restrict__ ecnt,
                                                   const float* __restrict__ fw,
                                                   float* __restrict__ moe_acc) {
  __shared__ int tok[128];
  __shared__ float wts[128];
  __shared__ __align__(16) short As[128 * 72];
  __shared__ __align__(16) short Bs[128 * 72];
  int tid = threadIdx.x;
  int bx = blockIdx.x;
  int lane = tid & 63, wid = tid >> 6;
  bool sh = bx >= 256;
  int e = 0, base, rows;
  const float* wd;
  const short* actp;
  if (!sh) {
    e = bx >> 2; base = (bx & 3) * 128;
    int cnt = ecnt[e];
    if (base >= cnt) return;
    rows = cnt - base; if (rows > 128) rows = 128;
    wd = w_dn + (size_t)e * FI_DIM * H_DIM;
    actp = actR + (size_t)(e * CAP + base) * FI_DIM;
  } else {
    base = (bx - 256) * 128; rows = 128;
    wd = sw_dn;
    actp = actS + (size_t)base * FI_DIM;
  }
  if (tid < 128) {
    if (sh) { tok[tid] = base + tid; wts[tid] = 1.f; }
    else if (tid < rows) {
      int pi = perm[e * CAP + base + tid];
      tok[tid] = pi >> 3;
      wts[tid] = fw[pi];
    } else { tok[tid] = 0; wts[tid] = 0.f; }
  }
  __syncthreads();
  int mh = (wid & 1) * 64, wn = (wid >> 1) * 64;
  for (int jc = 0; jc < 8; ++jc) {
    floatx4 acc[4][4] = {};
    for (int k0 = 0; k0 < FI_DIM; k0 += 64) {
      __syncthreads();
#pragma unroll
      for (int i = 0; i < 4; ++i) {
        int idx = tid + i * 256;
        int m = idx >> 3, c = idx & 7;
        *(int4*)(As + m * 72 + c * 8) =
            *(const int4*)(actp + (size_t)m * FI_DIM + k0 + c * 8);
      }
#pragma unroll
      for (int i = 0; i < 4; ++i) {
        int idx = tid + i * 256;
        int kc = idx >> 7, n2 = idx & 127;
        const float* wp = wd + (size_t)(k0 + kc * 8) * H_DIM + jc * 128 + n2;
        short8 b;
#pragma unroll
        for (int j = 0; j < 8; ++j) b[j] = f2bf(wp[(size_t)j * H_DIM]);
        *(short8*)(Bs + n2 * 72 + kc * 8) = b;
      }
      __syncthreads();
#pragma unroll
      for (int ks = 0; ks < 2; ++ks) {
        int ko = ks * 32 + (lane >> 4) * 8;
        short8 af[4], bfg[4];
#pragma unroll
        for (int t = 0; t < 4; ++t)
          af[t] = *(const short8*)(As + (mh + t * 16 + (lane & 15)) * 72 + ko);
#pragma unroll
        for (int t = 0; t < 4; ++t)
          bfg[t] = *(const short8*)(Bs + (wn + t * 16 + (lane & 15)) * 72 + ko);
#pragma unroll
        for (int mt = 0; mt < 4; ++mt)
#pragma unroll
          for (int nt = 0; nt < 4; ++nt)
            acc[mt][nt] = __builtin_amdgcn_mfma_f32_16x16x32_bf16(af[mt], bfg[nt], acc[mt][nt], 0, 0, 0);
      }
    }
    __syncthreads();
    int q = lane >> 4, cl = lane & 15;
#pragma unroll
    for (int mt = 0; mt < 4; ++mt)
#pragma unroll
      for (int nt = 0; nt < 4; ++nt)
#pragma unroll
        for (int r = 0; r < 4; ++r) {
          int row = mh + mt * 16 + q * 4 + r;
          if (row < rows) {
            int col = jc * 128 + wn + nt * 16 + cl;
            unsafeAtomicAdd(moe_acc + (size_t)tok[row] * H_DIM + col,
                            acc[mt][nt][r] * wts[row]);
          }
        }
  }
}

// ---------------- final combine ----------------
__global__ void combine_kernel(const float4* __restrict__ a, const float4* __restrict__ b,
                               float4* __restrict__ o) {
  size_t i = (size_t)blockIdx.x * 256 + threadIdx.x;
  float4 x = a[i], y = b[i];
  o[i] = make_float4(x.x + y.x, x.y + y.y, x.z + y.z, x.w + y.w);
}

extern "C" void kernel_launch(void* const* d_in, const int* in_sizes, int n_in,
                              void* d_out, int out_size, void* d_ws, size_t ws_size,
                              hipStream_t stream) {
  const float* x = (const float*)d_in[0];
  const int* positions = (const int*)d_in[1];
  const float* ln1_w = (const float*)d_in[2];
  const float* ln2_w = (const float*)d_in[3];
  const float* wqkv = (const float*)d_in[4];
  const float* bqkv = (const float*)d_in[5];
  const float* qn_w = (const float*)d_in[6];
  const float* kn_w = (const float*)d_in[7];
  const float* wo = (const float*)d_in[8];
  const float* gate_w = (const float*)d_in[9];
  const float* gate_b = (const float*)d_in[10];
  const float* w_gu = (const float*)d_in[11];
  const float* w_dn = (const float*)d_in[12];
  const float* sw_gu = (const float*)d_in[13];
  const float* sw_dn = (const float*)d_in[14];
  float* out = (float*)d_out;

  float* p = (float*)d_ws;
  float* h2 = p;        p += 2097152;
  float* xt = p;        p += 2097152;
  short* xtb = (short*)p; p += 1048576;
  float* moe_acc = p;   p += 2097152;
  float* fw = p;        p += 16384;
  int* topi = (int*)p;  p += 16384;
  int* perm = (int*)p;  p += 32768;
  int* ecnt = (int*)p;  p += 64;
  float* pool = p;
  // early-phase aliases
  short* h1b = (short*)pool;                 // T*H bf16 [0, 4MB)
  float* qkv = pool + 1048576;               // T*1536 fp32 [4MB, 16MB)
  short* attnb = (short*)(pool + 4194304);   // T*1024 bf16 [16MB, 20MB)
  short* qb_s  = (short*)(pool + 5242880);   // B*NH*S*D bf16 [20MB, 24MB)
  short* kb_s  = (short*)(pool + 6291456);   // B*NKV*S*D bf16 [24MB, 25MB)
  short* vtb_s = (short*)(pool + 6553600);   // B*NKV*D*S bf16 transposed [25MB, 26MB)
  // late-phase aliases (reuse same pool; earlier buffers dead by then)
  short* actR = (short*)pool;                // E*CAP*FI bf16 [0, 32MB)
  short* actS = (short*)(pool + 8388608);    // T*FI bf16 [32MB, 34MB)

  // 1. rmsnorm(x) -> h1 bf16
  rmsnorm_row<<<T_TOK, 256, 0, stream>>>(x, ln1_w, nullptr, h1b);
  // 2. qkv = h1 @ wqkv^T + bqkv  (MFMA)
  gemm_nt_mfma<<<dim3(QKV_DIM / 128, T_TOK / 128), 256, 0, stream>>>(
      h1b, wqkv, bqkv, nullptr, qkv, T_TOK, QKV_DIM, H_DIM);
  // 3. q/k rmsnorm + rope -> bf16 Q (scaled), K, V^T
  qknorm_rope<<<dim3(T_TOK, NHQ + 2 * NKV), 64, 0, stream>>>(qkv, positions, qn_w, kn_w,
                                                             qb_s, kb_s, vtb_s);
  // 4. MFMA flash attention -> attnb bf16
  attn_mfma<<<256, 256, 0, stream>>>(qb_s, kb_s, vtb_s, attnb);
  // 5. h2 = x + attn @ wo^T (MFMA)
  gemm_nt_mfma<<<dim3(H_DIM / 128, T_TOK / 128), 256, 0, stream>>>(
      attnb, wo, nullptr, x, h2, T_TOK, H_DIM, NHQ * D_HEAD);
  // 6. xt = rmsnorm(h2) (fp32 + bf16)
  rmsnorm_row<<<T_TOK, 256, 0, stream>>>(h2, ln2_w, xt, xtb);
  // 7. gating
  gating_kernel<<<T_TOK, 64, 0, stream>>>(xt, gate_w, gate_b, topi, fw);
  // 8. zero MoE accumulator
  zero_kernel<<<2048, 256, 0, stream>>>((float4*)moe_acc);
  // 9. parallel capacity scan
  scan_kernel<<<1, 256, 0, stream>>>(topi, perm, ecnt);
  // 10. F1: gu + silu (routed + shared fused in one grid)
  moe_gu_mfma<<<256 + T_TOK / 128, 256, 0, stream>>>(xtb, w_gu, sw_gu, perm, ecnt, actR, actS);
  // 11. F2: dn + weighted scatter
  moe_dn_mfma<<<256 + T_TOK / 128, 256, 0, stream>>>(actR, actS, w_dn, sw_dn, perm, ecnt, fw, moe_acc);
  // 12. out = h2 + moe
  combine_kernel<<<2048, 256, 0, stream>>>((const float4*)h2, (const float4*)moe_acc, (float4*)out);
}

// Round 3
// 1562.707 us; speedup vs baseline: 1.7900x; 1.1132x over previous
//
#include <hip/hip_runtime.h>
#include <math.h>

#define S_LEN 1024
#define B_SZ 2
#define H_DIM 1024
#define NHQ 8
#define NKV 2
#define D_HEAD 128
#define NE 64
#define TOPK 8
#define NGRP 8
#define TGRP 4
#define FI_DIM 512
#define CAP 512
#define EPS_F 1e-5f
#define T_TOK (B_SZ * S_LEN)               // 2048
#define QKV_DIM ((NHQ + 2 * NKV) * D_HEAD) // 1536
#define SCALE_F 0.08838834764831845f       // 1/sqrt(128)

typedef __attribute__((ext_vector_type(8))) short short8;
typedef __attribute__((ext_vector_type(4))) float floatx4;

__device__ inline short f2bf(float f) {
  union { float f; unsigned u; } v; v.f = f;
  unsigned r = (v.u + 0x7FFFu + ((v.u >> 16) & 1u)) >> 16;
  return (short)(r & 0xFFFFu);
}
__device__ inline float bf2f(short s) {
  union { unsigned u; float f; } v; v.u = ((unsigned)(unsigned short)s) << 16;
  return v.f;
}

// ---------------- RMSNorm: writes bf16 always, fp32 optionally ----------------
__global__ __launch_bounds__(256) void rmsnorm_row(const float* __restrict__ x,
                                                   const float* __restrict__ w,
                                                   float* __restrict__ outf,
                                                   short* __restrict__ outb) {
  int t = blockIdx.x;
  int tid = threadIdx.x;
  const float* xp = x + (size_t)t * H_DIM;
  float4 v = *(const float4*)(xp + tid * 4);
  float ss = v.x * v.x + v.y * v.y + v.z * v.z + v.w * v.w;
  for (int i = 1; i < 64; i <<= 1) ss += __shfl_xor(ss, i);
  __shared__ float red[4];
  if ((tid & 63) == 0) red[tid >> 6] = ss;
  __syncthreads();
  float tot = red[0] + red[1] + red[2] + red[3];
  float rs = rsqrtf(tot / (float)H_DIM + EPS_F);
  float4 wv = *(const float4*)(w + tid * 4);
  float4 o;
  o.x = v.x * rs * wv.x; o.y = v.y * rs * wv.y;
  o.z = v.z * rs * wv.z; o.w = v.w * rs * wv.w;
  if (outf) *(float4*)(outf + (size_t)t * H_DIM + tid * 4) = o;
  short* bp = outb + (size_t)t * H_DIM + tid * 4;
  bp[0] = f2bf(o.x); bp[1] = f2bf(o.y); bp[2] = f2bf(o.z); bp[3] = f2bf(o.w);
}

// ---------------- MFMA NT GEMM: C[M,N] = A(bf16)[M,K] @ W(fp32)[N,K]^T (+bias)(+res) ----------------
__global__ __launch_bounds__(256) void gemm_nt_mfma(const short* __restrict__ A,
                                                    const float* __restrict__ W,
                                                    const float* __restrict__ bias,
                                                    const float* __restrict__ res,
                                                    float* __restrict__ C,
                                                    int M, int N, int K) {
  __shared__ __align__(16) short As[128 * 72];
  __shared__ __align__(16) short Bs[128 * 72];
  int tid = threadIdx.x;
  int m0 = blockIdx.y * 128, n0 = blockIdx.x * 128;
  int lane = tid & 63, wid = tid >> 6;
  int wm = (wid & 1) * 64, wn = (wid >> 1) * 64;
  floatx4 acc[4][4] = {};
  for (int k0 = 0; k0 < K; k0 += 64) {
    __syncthreads();
#pragma unroll
    for (int i = 0; i < 4; ++i) {
      int idx = tid + i * 256;
      int m = idx >> 3, c = idx & 7;
      *(int4*)(As + m * 72 + c * 8) = *(const int4*)(A + (size_t)(m0 + m) * K + k0 + c * 8);
    }
#pragma unroll
    for (int i = 0; i < 4; ++i) {
      int idx = tid + i * 256;
      int n = idx >> 3, c = idx & 7;
      const float* wp = W + (size_t)(n0 + n) * K + k0 + c * 8;
      float4 v0 = *(const float4*)(wp);
      float4 v1 = *(const float4*)(wp + 4);
      short8 b;
      b[0] = f2bf(v0.x); b[1] = f2bf(v0.y); b[2] = f2bf(v0.z); b[3] = f2bf(v0.w);
      b[4] = f2bf(v1.x); b[5] = f2bf(v1.y); b[6] = f2bf(v1.z); b[7] = f2bf(v1.w);
      *(short8*)(Bs + n * 72 + c * 8) = b;
    }
    __syncthreads();
#pragma unroll
    for (int ks = 0; ks < 2; ++ks) {
      int ko = ks * 32 + (lane >> 4) * 8;
      short8 af[4], bfg[4];
#pragma unroll
      for (int t = 0; t < 4; ++t)
        af[t] = *(const short8*)(As + (wm + t * 16 + (lane & 15)) * 72 + ko);
#pragma unroll
      for (int t = 0; t < 4; ++t)
        bfg[t] = *(const short8*)(Bs + (wn + t * 16 + (lane & 15)) * 72 + ko);
#pragma unroll
      for (int mt = 0; mt < 4; ++mt)
#pragma unroll
        for (int nt = 0; nt < 4; ++nt)
          acc[mt][nt] = __builtin_amdgcn_mfma_f32_16x16x32_bf16(af[mt], bfg[nt], acc[mt][nt], 0, 0, 0);
    }
  }
  int q = lane >> 4, cl = lane & 15;
#pragma unroll
  for (int mt = 0; mt < 4; ++mt)
#pragma unroll
    for (int nt = 0; nt < 4; ++nt)
#pragma unroll
      for (int r = 0; r < 4; ++r) {
        int m = m0 + wm + mt * 16 + q * 4 + r;
        int n = n0 + wn + nt * 16 + cl;
        float v = acc[mt][nt][r];
        if (bias) v += bias[n];
        if (res) v += res[(size_t)m * N + n];
        C[(size_t)m * N + n] = v;
      }
}

// ---------------- per-head q/k RMSNorm + partial rope; emits bf16 Q (pre-scaled),
// bf16 K, and bf16 transposed V for the MFMA attention ----------------
__global__ __launch_bounds__(64) void qknorm_rope(const float* __restrict__ qkv,
                                                  const int* __restrict__ positions,
                                                  const float* __restrict__ qn_w,
                                                  const float* __restrict__ kn_w,
                                                  short* __restrict__ qbo,
                                                  short* __restrict__ kbo,
                                                  short* __restrict__ vtbo) {
  int t = blockIdx.x;
  int head = blockIdx.y;
  int lane = threadIdx.x;
  int b = t >> 10;
  int s = t & (S_LEN - 1);
  if (head >= NHQ + NKV) {  // V heads: bf16 convert + transpose to [b][kvh][d][s]
    int kvh = head - (NHQ + NKV);
    const float* vp = qkv + (size_t)t * QKV_DIM + (NHQ + NKV) * D_HEAD + kvh * D_HEAD;
    short* vt = vtbo + (size_t)(b * NKV + kvh) * D_HEAD * S_LEN + s;
    vt[(size_t)lane * S_LEN] = f2bf(vp[lane]);
    vt[(size_t)(lane + 64) * S_LEN] = f2bf(vp[lane + 64]);
    return;
  }
  bool isq = head < NHQ;
  int off = isq ? head * D_HEAD : (NHQ * D_HEAD + (head - NHQ) * D_HEAD);
  const float* ptr = qkv + (size_t)t * QKV_DIM + off;
  const float* w = isq ? qn_w : kn_w;
  float x0 = ptr[lane];
  float x1 = ptr[lane + 64];
  float ss = x0 * x0 + x1 * x1;
  for (int i = 1; i < 64; i <<= 1) ss += __shfl_xor(ss, i);
  float rs = rsqrtf(ss / (float)D_HEAD + EPS_F);
  x0 = x0 * rs * w[lane];
  x1 = x1 * rs * w[lane + 64];
  float pos = (float)positions[s];
  int i2 = lane & 31;
  float invf = powf(10000.0f, -(float)i2 / 32.0f);
  float ang = pos * invf;
  float c = cosf(ang), sn = sinf(ang);
  float other = __shfl_xor(x0, 32);
  float r = (lane < 32) ? (x0 * c - other * sn) : (x0 * c + other * sn);
  if (isq) {
    short* qo = qbo + ((size_t)(b * NHQ + head) * S_LEN + s) * D_HEAD;
    qo[lane] = f2bf(r * SCALE_F);
    qo[lane + 64] = f2bf(x1 * SCALE_F);
  } else {
    short* ko = kbo + ((size_t)(b * NKV + (head - NHQ)) * S_LEN + s) * D_HEAD;
    ko[lane] = f2bf(r);
    ko[lane + 64] = f2bf(x1);
  }
}

// ---------------- MFMA flash attention (causal GQA), bf16 in, bf16 out ----------------
__global__ __launch_bounds__(256) void attn_mfma(const short* __restrict__ qb,
                                                 const short* __restrict__ kb,
                                                 const short* __restrict__ vtb,
                                                 short* __restrict__ attnout) {
  __shared__ __align__(16) short Pb[4][16 * 36];  // per-wave P tile, 72B stride (bank-conflict-free)
  int tid = threadIdx.x;
  int lane = tid & 63, wid = tid >> 6;
  int l15 = lane & 15, l4 = lane >> 4;
  int bx = blockIdx.x;
  int bh = bx >> 4;            // 0..15 = b*8+h
  int g = bx & 15;
  int qt = (wid == 0) ? g : (wid == 1) ? (31 - g) : (wid == 2) ? (32 + g) : (63 - g);
  int b = bh >> 3, h = bh & 7, kvh = h >> 2;
  int qb0 = qt * 16;
  short* Pw = Pb[wid];

  const short* qp = qb + ((size_t)(b * NHQ + h) * S_LEN + qb0 + l15) * D_HEAD + l4 * 8;
  short8 qf[4];
#pragma unroll
  for (int c = 0; c < 4; ++c) qf[c] = *(const short8*)(qp + c * 32);

  const short* kbp = kb + (size_t)(b * NKV + kvh) * S_LEN * D_HEAD;
  const short* vbp = vtb + (size_t)(b * NKV + kvh) * D_HEAD * S_LEN;

  float m[4] = {-1e30f, -1e30f, -1e30f, -1e30f};
  float l[4] = {0.f, 0.f, 0.f, 0.f};
  floatx4 o[8] = {};

  int nkt = qb0 / 32 + 1;
  for (int kt = 0; kt < nkt; ++kt) {
    int kb0 = kt * 32;
    const short* kp = kbp + (size_t)(kb0 + l15) * D_HEAD + l4 * 8;
    floatx4 s0 = {}, s1 = {};
#pragma unroll
    for (int c = 0; c < 4; ++c) {
      short8 k0 = *(const short8*)(kp + c * 32);
      short8 k1 = *(const short8*)(kp + 16 * D_HEAD + c * 32);
      s0 = __builtin_amdgcn_mfma_f32_16x16x32_bf16(qf[c], k0, s0, 0, 0, 0);
      s1 = __builtin_amdgcn_mfma_f32_16x16x32_bf16(qf[c], k1, s1, 0, 0, 0);
    }
    if (kt == nkt - 1) {
#pragma unroll
      for (int r = 0; r < 4; ++r) {
        int qrow = qb0 + l4 * 4 + r;
        if (kb0 + l15 > qrow) s0[r] = -1e30f;
        if (kb0 + 16 + l15 > qrow) s1[r] = -1e30f;
      }
    }
    float al[4];
#pragma unroll
    for (int r = 0; r < 4; ++r) {
      float tm = fmaxf(s0[r], s1[r]);
      tm = fmaxf(tm, __shfl_xor(tm, 1));
      tm = fmaxf(tm, __shfl_xor(tm, 2));
      tm = fmaxf(tm, __shfl_xor(tm, 4));
      tm = fmaxf(tm, __shfl_xor(tm, 8));
      float mn = fmaxf(m[r], tm);
      al[r] = __expf(m[r] - mn);
      m[r] = mn;
      float p0 = __expf(s0[r] - mn);
      float p1 = __expf(s1[r] - mn);
      s0[r] = p0; s1[r] = p1;
      float ts = p0 + p1;
      ts += __shfl_xor(ts, 1);
      ts += __shfl_xor(ts, 2);
      ts += __shfl_xor(ts, 4);
      ts += __shfl_xor(ts, 8);
      l[r] = l[r] * al[r] + ts;
    }
#pragma unroll
    for (int dt = 0; dt < 8; ++dt)
#pragma unroll
      for (int r = 0; r < 4; ++r) o[dt][r] *= al[r];
    __builtin_amdgcn_wave_barrier();
#pragma unroll
    for (int r = 0; r < 4; ++r) {
      int prow = l4 * 4 + r;
      Pw[prow * 36 + l15] = f2bf(s0[r]);
      Pw[prow * 36 + 16 + l15] = f2bf(s1[r]);
    }
    __builtin_amdgcn_wave_barrier();
    short4 pa0 = *(const short4*)(Pw + l15 * 36 + l4 * 8);
    short4 pa1 = *(const short4*)(Pw + l15 * 36 + l4 * 8 + 4);
    short8 pf;
    pf[0] = pa0.x; pf[1] = pa0.y; pf[2] = pa0.z; pf[3] = pa0.w;
    pf[4] = pa1.x; pf[5] = pa1.y; pf[6] = pa1.z; pf[7] = pa1.w;
#pragma unroll
    for (int dt = 0; dt < 8; ++dt) {
      short8 vf = *(const short8*)(vbp + (size_t)(dt * 16 + l15) * S_LEN + kb0 + l4 * 8);
      o[dt] = __builtin_amdgcn_mfma_f32_16x16x32_bf16(pf, vf, o[dt], 0, 0, 0);
    }
  }
  float inv[4];
#pragma unroll
  for (int r = 0; r < 4; ++r) inv[r] = 1.f / l[r];
#pragma unroll
  for (int dt = 0; dt < 8; ++dt)
#pragma unroll
    for (int r = 0; r < 4; ++r) {
      int qrow = qb0 + l4 * 4 + r;
      attnout[(size_t)(b * S_LEN + qrow) * (NHQ * D_HEAD) + h * D_HEAD + dt * 16 + l15] =
          f2bf(o[dt][r] * inv[r]);
    }
}

// ---------------- gate_w [64][1024] -> gwT [1024][64] (LDS tile transpose) ----------------
__global__ __launch_bounds__(256) void gate_transpose(const float* __restrict__ gw,
                                                      float* __restrict__ gwT) {
  __shared__ float tile[64][65];
  int k0 = blockIdx.x * 64;
  int tid = threadIdx.x;
  for (int i = tid; i < 64 * 64; i += 256) {
    int e = i >> 6, ki = i & 63;
    tile[e][ki] = gw[(size_t)e * H_DIM + k0 + ki];
  }
  __syncthreads();
  for (int i = tid; i < 64 * 64; i += 256) {
    int ki = i >> 6, e = i & 63;
    gwT[(size_t)(k0 + ki) * NE + e] = tile[e][ki];
  }
}

// ---------------- gating: fp32 logits GEMM + sigmoid + group/expert top-k ----------------
// 128 blocks x 16 tokens. Lane e reads gwT[k*64+e] (coalesced, L2-hot).
// Each thread: 4 tokens x 4 fp32 k-partials. Selection logic identical to reference.
__global__ __launch_bounds__(256) void gate_kernel(const float* __restrict__ xt,
                                                   const float* __restrict__ gwT,
                                                   const float* __restrict__ gate_b,
                                                   int* __restrict__ topi,
                                                   float* __restrict__ fw) {
  __shared__ float xs[16][H_DIM];      // 64 KB
  __shared__ float scs[16][NE];
  __shared__ float corrs[16][NE];
  __shared__ float grps[16][NGRP];
  int tid = threadIdx.x;
  int t0 = blockIdx.x * 16;
  for (int i = tid; i < 16 * 256; i += 256) {
    int t = i >> 8, c = i & 255;
    *(float4*)&xs[t][c * 4] = *(const float4*)(xt + (size_t)(t0 + t) * H_DIM + c * 4);
  }
  __syncthreads();
  int e = tid & 63, tq = tid >> 6;  // tq in 0..3 -> tokens tq*4 .. tq*4+3
  const float* x0 = xs[tq * 4 + 0];
  const float* x1 = xs[tq * 4 + 1];
  const float* x2 = xs[tq * 4 + 2];
  const float* x3 = xs[tq * 4 + 3];
  floatx4 a0 = {}, a1 = {}, a2 = {}, a3 = {};
  for (int k = 0; k < H_DIM; k += 4) {
    float w0 = gwT[(size_t)(k + 0) * NE + e];
    float w1 = gwT[(size_t)(k + 1) * NE + e];
    float w2 = gwT[(size_t)(k + 2) * NE + e];
    float w3 = gwT[(size_t)(k + 3) * NE + e];
    float4 v0 = *(const float4*)(x0 + k);
    float4 v1 = *(const float4*)(x1 + k);
    float4 v2 = *(const float4*)(x2 + k);
    float4 v3 = *(const float4*)(x3 + k);
    a0[0] = fmaf(v0.x, w0, a0[0]); a0[1] = fmaf(v0.y, w1, a0[1]);
    a0[2] = fmaf(v0.z, w2, a0[2]); a0[3] = fmaf(v0.w, w3, a0[3]);
    a1[0] = fmaf(v1.x, w0, a1[0]); a1[1] = fmaf(v1.y, w1, a1[1]);
    a1[2] = fmaf(v1.z, w2, a1[2]); a1[3] = fmaf(v1.w, w3, a1[3]);
    a2[0] = fmaf(v2.x, w0, a2[0]); a2[1] = fmaf(v2.y, w1, a2[1]);
    a2[2] = fmaf(v2.z, w2, a2[2]); a2[3] = fmaf(v2.w, w3, a2[3]);
    a3[0] = fmaf(v3.x, w0, a3[0]); a3[1] = fmaf(v3.y, w1, a3[1]);
    a3[2] = fmaf(v3.z, w2, a3[2]); a3[3] = fmaf(v3.w, w3, a3[3]);
  }
  float b = gate_b[e];
  float lg[4];
  lg[0] = (a0[0] + a0[1]) + (a0[2] + a0[3]);
  lg[1] = (a1[0] + a1[1]) + (a1[2] + a1[3]);
  lg[2] = (a2[0] + a2[1]) + (a2[2] + a2[3]);
  lg[3] = (a3[0] + a3[1]) + (a3[2] + a3[3]);
#pragma unroll
  for (int j = 0; j < 4; ++j) {
    float s = 1.f / (1.f + expf(-lg[j]));
    scs[tq * 4 + j][e] = s;
    corrs[tq * 4 + j][e] = s + b;
  }
  __syncthreads();
  if (tid < 128) {  // group top-2 sums: (token, group)
    int t = tid >> 3, g = tid & 7;
    float m1 = -1e30f, m2 = -1e30f;
    for (int j = 0; j < NE / NGRP; ++j) {
      float v = corrs[t][g * 8 + j];
      if (v > m1) { m2 = m1; m1 = v; }
      else if (v > m2) m2 = v;
    }
    grps[t][g] = m1 + m2;
  }
  __syncthreads();
  if (tid < 16) {  // per-token serial selection (reference semantics)
    int t = tid;
    bool gsel[NGRP];
    for (int g = 0; g < NGRP; ++g) gsel[g] = false;
    for (int it = 0; it < TGRP; ++it) {
      int bi = -1; float bv = -1e30f;
      for (int g = 0; g < NGRP; ++g)
        if (!gsel[g] && grps[t][g] > bv) { bv = grps[t][g]; bi = g; }
      gsel[bi] = true;
    }
    bool ch[NE];
    for (int i2 = 0; i2 < NE; ++i2) ch[i2] = false;
    int sel[TOPK];
    float wsum = 0.f;
    for (int it = 0; it < TOPK; ++it) {
      int bi = -1; float bv = -1e30f;
      for (int x2 = 0; x2 < NE; ++x2) {
        if (!gsel[x2 >> 3] || ch[x2]) continue;
        if (corrs[t][x2] > bv) { bv = corrs[t][x2]; bi = x2; }
      }
      ch[bi] = true;
      sel[it] = bi;
      wsum += scs[t][bi];
    }
    float invw = 1.f / wsum;
    int gt = t0 + t;
    for (int it = 0; it < TOPK; ++it) {
      topi[gt * TOPK + it] = sel[it];
      fw[gt * TOPK + it] = scs[t][sel[it]] * invw;
    }
  }
}

// ---------------- parallel ordered capacity scan: 1 block, 256 threads ----------------
__global__ __launch_bounds__(256) void scan_kernel(const int* __restrict__ topi,
                                                   int* __restrict__ perm,
                                                   int* __restrict__ ecnt) {
  __shared__ int hist[256 * 65];
  int tid = threadIdx.x;
  for (int i = tid; i < 256 * 65; i += 256) hist[i] = 0;
  __syncthreads();
  int loc[64];
#pragma unroll
  for (int j = 0; j < 64; j += 4) {
    int4 v = *(const int4*)(topi + tid * 64 + j);
    loc[j] = v.x; loc[j + 1] = v.y; loc[j + 2] = v.z; loc[j + 3] = v.w;
  }
#pragma unroll
  for (int j = 0; j < 64; ++j) hist[tid * 65 + loc[j]]++;
  __syncthreads();
  if (tid < 64) {
    int run = 0;
    for (int c = 0; c < 256; ++c) {
      int v = hist[c * 65 + tid];
      hist[c * 65 + tid] = run;
      run += v;
    }
    ecnt[tid] = run < CAP ? run : CAP;
  }
  __syncthreads();
#pragma unroll
  for (int j = 0; j < 64; ++j) {
    int e = loc[j];
    int pos = hist[tid * 65 + e]++;
    if (pos < CAP) perm[e * CAP + pos] = tid * 64 + j;
  }
}

__global__ void zero_kernel(float4* __restrict__ p) {
  p[(size_t)blockIdx.x * 256 + threadIdx.x] = make_float4(0.f, 0.f, 0.f, 0.f);
}

// ---------------- F1: act = silu(X Wg) * (X Wu), MFMA, bf16 out ----------------
__global__ __launch_bounds__(256) void moe_gu_mfma(const short* __restrict__ xtb,
                                                   const float* __restrict__ w_gu,
                                                   const float* __restrict__ sw_gu,
                                                   const int* __restrict__ perm,
                                                   const int* __restrict__ ecnt,
                                                   short* __restrict__ actR,
                                                   short* __restrict__ actS) {
  __shared__ int tok[128];
  __shared__ __align__(16) short As[128 * 72];
  __shared__ __align__(16) short Bs[128 * 72];
  int tid = threadIdx.x;
  int bx = blockIdx.x;
  int lane = tid & 63, wid = tid >> 6;
  bool sh = bx >= 256;
  int e = 0, base, rows;
  const float* wg;
  short* actp;
  if (!sh) {
    e = bx >> 2; base = (bx & 3) * 128;
    int cnt = ecnt[e];
    if (base >= cnt) return;
    rows = cnt - base; if (rows > 128) rows = 128;
    wg = w_gu + (size_t)e * H_DIM * (2 * FI_DIM);
    actp = actR + (size_t)(e * CAP + base) * FI_DIM;
  } else {
    base = (bx - 256) * 128; rows = 128;
    wg = sw_gu;
    actp = actS + (size_t)base * FI_DIM;
  }
  if (tid < 128) {
    int m = tid < rows ? tid : (rows - 1);
    tok[tid] = sh ? (base + tid) : (perm[e * CAP + base + m] >> 3);
  }
  __syncthreads();
  int mh = (wid & 1) * 64;
  int uh = wid >> 1;
  for (int jc = 0; jc < 8; ++jc) {
    floatx4 acc[4][4] = {};
    for (int k0 = 0; k0 < H_DIM; k0 += 64) {
      __syncthreads();
#pragma unroll
      for (int i = 0; i < 4; ++i) {
        int idx = tid + i * 256;
        int m = idx >> 3, c = idx & 7;
        *(int4*)(As + m * 72 + c * 8) =
            *(const int4*)(xtb + (size_t)tok[m] * H_DIM + k0 + c * 8);
      }
#pragma unroll
      for (int i = 0; i < 4; ++i) {
        int idx = tid + i * 256;
        int kc = idx >> 7, n2 = idx & 127;
        int col = (n2 < 64) ? (jc * 64 + n2) : (FI_DIM + jc * 64 + (n2 - 64));
        const float* wp = wg + (size_t)(k0 + kc * 8) * (2 * FI_DIM) + col;
        short8 b;
#pragma unroll
        for (int j = 0; j < 8; ++j) b[j] = f2bf(wp[(size_t)j * (2 * FI_DIM)]);
        *(short8*)(Bs + n2 * 72 + kc * 8) = b;
      }
      __syncthreads();
#pragma unroll
      for (int ks = 0; ks < 2; ++ks) {
        int ko = ks * 32 + (lane >> 4) * 8;
        short8 af[4], bfg[4];
#pragma unroll
        for (int t = 0; t < 4; ++t)
          af[t] = *(const short8*)(As + (mh + t * 16 + (lane & 15)) * 72 + ko);
#pragma unroll
        for (int t = 0; t < 4; ++t)
          bfg[t] = *(const short8*)(Bs + (uh * 64 + t * 16 + (lane & 15)) * 72 + ko);
#pragma unroll
        for (int mt = 0; mt < 4; ++mt)
#pragma unroll
          for (int nt = 0; nt < 4; ++nt)
            acc[mt][nt] = __builtin_amdgcn_mfma_f32_16x16x32_bf16(af[mt], bfg[nt], acc[mt][nt], 0, 0, 0);
      }
    }
    __syncthreads();
    int q = lane >> 4, cl = lane & 15;
    if (uh == 0) {
#pragma unroll
      for (int mt = 0; mt < 4; ++mt)
#pragma unroll
        for (int nt = 0; nt < 4; ++nt)
#pragma unroll
          for (int r = 0; r < 4; ++r) {
            int row = mh + mt * 16 + q * 4 + r;
            int col = nt * 16 + cl;
            Bs[row * 72 + col] = f2bf(acc[mt][nt][r]);
          }
    }
    __syncthreads();
    if (uh == 1) {
#pragma unroll
      for (int mt = 0; mt < 4; ++mt)
#pragma unroll
        for (int nt = 0; nt < 4; ++nt)
#pragma unroll
          for (int r = 0; r < 4; ++r) {
            int row = mh + mt * 16 + q * 4 + r;
            int col = nt * 16 + cl;
            float g = bf2f(Bs[row * 72 + col]);
            float u = acc[mt][nt][r];
            float a = g / (1.f + expf(-g)) * u;
            actp[(size_t)row * FI_DIM + jc * 64 + col] = f2bf(a);
          }
    }
  }
}

// ---------------- F2: out += (act Wdn) * w, MFMA, atomic scatter ----------------
__global__ __launch_bounds__(256) void moe_dn_mfma(const short* __restrict__ actR,
                                                   const short* __restrict__ actS,
                                                   const float* __restrict__ w_dn,
                                                   const float* __restrict__ sw_dn,
                                                   const int* __restrict__ perm,
                                                   const int* __restrict__ ecnt,
                                                   const float* __restrict__ fw,
                                                   float* __restrict__ moe_acc) {
  __shared__ int tok[128];
  __shared__ float wts[128];
  __shared__ __align__(16) short As[128 * 72];
  __shared__ __align__(16) short Bs[128 * 72];
  int tid = threadIdx.x;
  int bx = blockIdx.x;
  int lane = tid & 63, wid = tid >> 6;
  bool sh = bx >= 256;
  int e = 0, base, rows;
  const float* wd;
  const short* actp;
  if (!sh) {
    e = bx >> 2; base = (bx & 3) * 128;
    int cnt = ecnt[e];
    if (base >= cnt) return;
    rows = cnt - base; if (rows > 128) rows = 128;
    wd = w_dn + (size_t)e * FI_DIM * H_DIM;
    actp = actR + (size_t)(e * CAP + base) * FI_DIM;
  } else {
    base = (bx - 256) * 128; rows = 128;
    wd = sw_dn;
    actp = actS + (size_t)base * FI_DIM;
  }
  if (tid < 128) {
    if (sh) { tok[tid] = base + tid; wts[tid] = 1.f; }
    else if (tid < rows) {
      int pi = perm[e * CAP + base + tid];
      tok[tid] = pi >> 3;
      wts[tid] = fw[pi];
    } else { tok[tid] = 0; wts[tid] = 0.f; }
  }
  __syncthreads();
  int mh = (wid & 1) * 64, wn = (wid >> 1) * 64;
  for (int jc = 0; jc < 8; ++jc) {
    floatx4 acc[4][4] = {};
    for (int k0 = 0; k0 < FI_DIM; k0 += 64) {
      __syncthreads();
#pragma unroll
      for (int i = 0; i < 4; ++i) {
        int idx = tid + i * 256;
        int m = idx >> 3, c = idx & 7;
        *(int4*)(As + m * 72 + c * 8) =
            *(const int4*)(actp + (size_t)m * FI_DIM + k0 + c * 8);
      }
#pragma unroll
      for (int i = 0; i < 4; ++i) {
        int idx = tid + i * 256;
        int kc = idx >> 7, n2 = idx & 127;
        const float* wp = wd + (size_t)(k0 + kc * 8) * H_DIM + jc * 128 + n2;
        short8 b;
#pragma unroll
        for (int j = 0; j < 8; ++j) b[j] = f2bf(wp[(size_t)j * H_DIM]);
        *(short8*)(Bs + n2 * 72 + kc * 8) = b;
      }
      __syncthreads();
#pragma unroll
      for (int ks = 0; ks < 2; ++ks) {
        int ko = ks * 32 + (lane >> 4) * 8;
        short8 af[4], bfg[4];
#pragma unroll
        for (int t = 0; t < 4; ++t)
          af[t] = *(const short8*)(As + (mh + t * 16 + (lane & 15)) * 72 + ko);
#pragma unroll
        for (int t = 0; t < 4; ++t)
          bfg[t] = *(const short8*)(Bs + (wn + t * 16 + (lane & 15)) * 72 + ko);
#pragma unroll
        for (int mt = 0; mt < 4; ++mt)
#pragma unroll
          for (int nt = 0; nt < 4; ++nt)
            acc[mt][nt] = __builtin_amdgcn_mfma_f32_16x16x32_bf16(af[mt], bfg[nt], acc[mt][nt], 0, 0, 0);
      }
    }
    __syncthreads();
    int q = lane >> 4, cl = lane & 15;
#pragma unroll
    for (int mt = 0; mt < 4; ++mt)
#pragma unroll
      for (int nt = 0; nt < 4; ++nt)
#pragma unroll
        for (int r = 0; r < 4; ++r) {
          int row = mh + mt * 16 + q * 4 + r;
          if (row < rows) {
            int col = jc * 128 + wn + nt * 16 + cl;
            unsafeAtomicAdd(moe_acc + (size_t)tok[row] * H_DIM + col,
                            acc[mt][nt][r] * wts[row]);
          }
        }
  }
}

// ---------------- final combine ----------------
__global__ void combine_kernel(const float4* __restrict__ a, const float4* __restrict__ b,
                               float4* __restrict__ o) {
  size_t i = (size_t)blockIdx.x * 256 + threadIdx.x;
  float4 x = a[i], y = b[i];
  o[i] = make_float4(x.x + y.x, x.y + y.y, x.z + y.z, x.w + y.w);
}

extern "C" void kernel_launch(void* const* d_in, const int* in_sizes, int n_in,
                              void* d_out, int out_size, void* d_ws, size_t ws_size,
                              hipStream_t stream) {
  const float* x = (const float*)d_in[0];
  const int* positions = (const int*)d_in[1];
  const float* ln1_w = (const float*)d_in[2];
  const float* ln2_w = (const float*)d_in[3];
  const float* wqkv = (const float*)d_in[4];
  const float* bqkv = (const float*)d_in[5];
  const float* qn_w = (const float*)d_in[6];
  const float* kn_w = (const float*)d_in[7];
  const float* wo = (const float*)d_in[8];
  const float* gate_w = (const float*)d_in[9];
  const float* gate_b = (const float*)d_in[10];
  const float* w_gu = (const float*)d_in[11];
  const float* w_dn = (const float*)d_in[12];
  const float* sw_gu = (const float*)d_in[13];
  const float* sw_dn = (const float*)d_in[14];
  float* out = (float*)d_out;

  float* p = (float*)d_ws;
  float* h2 = p;        p += 2097152;
  float* xt = p;        p += 2097152;
  short* xtb = (short*)p; p += 1048576;
  float* moe_acc = p;   p += 2097152;
  float* fw = p;        p += 16384;
  int* topi = (int*)p;  p += 16384;
  int* perm = (int*)p;  p += 32768;
  int* ecnt = (int*)p;  p += 64;
  float* gwT = p;       p += 65536;          // 1024x64 fp32 transposed gate_w
  float* pool = p;
  // early-phase aliases
  short* h1b = (short*)pool;                 // T*H bf16 [0, 4MB)
  float* qkv = pool + 1048576;               // T*1536 fp32 [4MB, 16MB)
  short* attnb = (short*)(pool + 4194304);   // T*1024 bf16 [16MB, 20MB)
  short* qb_s  = (short*)(pool + 5242880);   // B*NH*S*D bf16 [20MB, 24MB)
  short* kb_s  = (short*)(pool + 6291456);   // B*NKV*S*D bf16 [24MB, 25MB)
  short* vtb_s = (short*)(pool + 6553600);   // B*NKV*D*S bf16 transposed [25MB, 26MB)
  // late-phase aliases (reuse same pool; earlier buffers dead by then)
  short* actR = (short*)pool;                // E*CAP*FI bf16 [0, 32MB)
  short* actS = (short*)(pool + 8388608);    // T*FI bf16 [32MB, 34MB)

  // 0. gate_w transpose (needed later; launch early)
  gate_transpose<<<16, 256, 0, stream>>>(gate_w, gwT);
  // 1. rmsnorm(x) -> h1 bf16
  rmsnorm_row<<<T_TOK, 256, 0, stream>>>(x, ln1_w, nullptr, h1b);
  // 2. qkv = h1 @ wqkv^T + bqkv  (MFMA)
  gemm_nt_mfma<<<dim3(QKV_DIM / 128, T_TOK / 128), 256, 0, stream>>>(
      h1b, wqkv, bqkv, nullptr, qkv, T_TOK, QKV_DIM, H_DIM);
  // 3. q/k rmsnorm + rope -> bf16 Q (scaled), K, V^T
  qknorm_rope<<<dim3(T_TOK, NHQ + 2 * NKV), 64, 0, stream>>>(qkv, positions, qn_w, kn_w,
                                                             qb_s, kb_s, vtb_s);
  // 4. MFMA flash attention -> attnb bf16
  attn_mfma<<<256, 256, 0, stream>>>(qb_s, kb_s, vtb_s, attnb);
  // 5. h2 = x + attn @ wo^T (MFMA)
  gemm_nt_mfma<<<dim3(H_DIM / 128, T_TOK / 128), 256, 0, stream>>>(
      attnb, wo, nullptr, x, h2, T_TOK, H_DIM, NHQ * D_HEAD);
  // 6. xt = rmsnorm(h2) (fp32 + bf16)
  rmsnorm_row<<<T_TOK, 256, 0, stream>>>(h2, ln2_w, xt, xtb);
  // 7. gating (fp32 GEMM + selection)
  gate_kernel<<<T_TOK / 16, 256, 0, stream>>>(xt, gwT, gate_b, topi, fw);
  // 8. zero MoE accumulator
  zero_kernel<<<2048, 256, 0, stream>>>((float4*)moe_acc);
  // 9. parallel capacity scan
  scan_kernel<<<1, 256, 0, stream>>>(topi, perm, ecnt);
  // 10. F1: gu + silu (routed + shared fused in one grid)
  moe_gu_mfma<<<256 + T_TOK / 128, 256, 0, stream>>>(xtb, w_gu, sw_gu, perm, ecnt, actR, actS);
  // 11. F2: dn + weighted scatter
  moe_dn_mfma<<<256 + T_TOK / 128, 256, 0, stream>>>(actR, actS, w_dn, sw_dn, perm, ecnt, fw, moe_acc);
  // 12. out = h2 + moe
  combine_kernel<<<2048, 256, 0, stream>>>((const float4*)h2, (const float4*)moe_acc, (float4*)out);
}